// Round 1
// baseline (958.773 us; speedup 1.0000x reference)
//
#include <hip/hip_runtime.h>
#include <math.h>

#define HWDIM 256
#define CH 32
#define NB 8
#define TILE 16
#define NLOC (NB*HWDIM*HWDIM)   /* 524288 locations */
#define R_CLAMP 4.9517189f      /* artanh(0.9999) */
#define MAXN 0.9999f            /* (1-1e-4)/sqrt(c) */
#define BN_EPS 1e-5f
#define EPSF 1e-5f

__device__ __forceinline__ float artanh_c(float n) {
    float t = fminf(n, 1.0f - 1e-5f);
    return 0.5f * (log1pf(t) - log1pf(-t));
}

// STAGE 1: staging transform = logmap0 (x is in the ball)
// STAGE 2: staging transform = bn1 (scale/shift) + clampnorm + relu
template<int STAGE>
__global__ __launch_bounds__(256) void conv_kernel(
    const float* __restrict__ src,
    const float* __restrict__ wt,      // [CH][CH][3][3]
    const float* __restrict__ bias,    // [CH]
    const float* __restrict__ scsh,    // [2*CH] scale,shift (STAGE 2 only)
    float* __restrict__ dst,
    float* __restrict__ partials)      // [nblocks][64] sums+sumsqs
{
    __shared__ float tile[CH][18][18];
    __shared__ float red[4][64];
    const int tid = threadIdx.x;
    const int bx = blockIdx.x, by = blockIdx.y, bz = blockIdx.z;
    const int h0 = by*TILE - 1, w0 = bx*TILE - 1;
    const float* srcn = src + (size_t)bz*CH*HWDIM*HWDIM;

    // ---- stage global -> LDS (zero halo outside image) ----
    for (int idx = tid; idx < CH*324; idx += 256) {
        int c = idx / 324;
        int r = idx - c*324;
        int y = r / 18, x = r - y*18;
        int gh = h0 + y, gw = w0 + x;
        float v = 0.0f;
        if (gh >= 0 && gh < HWDIM && gw >= 0 && gw < HWDIM)
            v = srcn[((size_t)c*HWDIM + gh)*HWDIM + gw];
        tile[c][y][x] = v;
    }
    __syncthreads();

    // ---- per-location channel transform in LDS ----
    for (int loc = tid; loc < 324; loc += 256) {
        int y = loc / 18, x = loc - y*18;
        int gh = h0 + y, gw = w0 + x;
        if (gh < 0 || gh >= HWDIM || gw < 0 || gw >= HWDIM) continue; // stays zero (padding)
        float v[CH];
        float n2 = 0.0f;
        if (STAGE == 1) {
            #pragma unroll
            for (int c = 0; c < CH; c++) { float t = tile[c][y][x]; v[c] = t; n2 += t*t; }
            float n = fmaxf(sqrtf(n2), EPSF);
            float f = artanh_c(n) / n;
            #pragma unroll
            for (int c = 0; c < CH; c++) tile[c][y][x] = v[c]*f;
        } else {
            #pragma unroll
            for (int c = 0; c < CH; c++) {
                float t = tile[c][y][x] * scsh[c] + scsh[CH + c];
                v[c] = t; n2 += t*t;
            }
            float n = sqrtf(n2);
            float f = (n > R_CLAMP) ? (R_CLAMP / n) : 1.0f;
            #pragma unroll
            for (int c = 0; c < CH; c++) tile[c][y][x] = fmaxf(v[c]*f, 0.0f);
        }
    }
    __syncthreads();

    // ---- direct 3x3 conv: each thread -> one (h,w), all 32 cout ----
    const int tx = tid & 15, ty = tid >> 4;
    float acc[CH];
    #pragma unroll
    for (int co = 0; co < CH; co++) acc[co] = bias[co];

    for (int ci = 0; ci < CH; ci++) {
        float win[9];
        #pragma unroll
        for (int k = 0; k < 9; k++) win[k] = tile[ci][ty + k/3][tx + (k - (k/3)*3)];
        const float* wci = wt + ci*9;          // wave-uniform -> s_load expected
        #pragma unroll
        for (int co = 0; co < CH; co++) {
            #pragma unroll
            for (int k = 0; k < 9; k++)
                acc[co] = fmaf(win[k], wci[co*(CH*9) + k], acc[co]);
        }
    }

    // ---- clampnorm epilogue + write + BN partial stats ----
    float n2 = 0.0f;
    #pragma unroll
    for (int co = 0; co < CH; co++) n2 += acc[co]*acc[co];
    float nn = sqrtf(n2);
    float f = (nn > R_CLAMP) ? (R_CLAMP / nn) : 1.0f;

    const int h = by*TILE + ty, w = bx*TILE + tx;
    float* dstn = dst + ((size_t)bz*CH*HWDIM + h)*HWDIM + w;
    const int wave = tid >> 6, lane = tid & 63;
    #pragma unroll
    for (int co = 0; co < CH; co++) {
        float val = acc[co] * f;
        dstn[(size_t)co*HWDIM*HWDIM] = val;
        float s = val, q = val*val;
        #pragma unroll
        for (int m = 1; m < 64; m <<= 1) {
            s += __shfl_xor(s, m, 64);
            q += __shfl_xor(q, m, 64);
        }
        if (lane == 0) { red[wave][co] = s; red[wave][CH + co] = q; }
    }
    __syncthreads();
    if (tid < 64) {
        float s = red[0][tid] + red[1][tid] + red[2][tid] + red[3][tid];
        int bid = (bz*gridDim.y + by)*gridDim.x + bx;
        partials[(size_t)bid*64 + tid] = s;
    }
}

__global__ __launch_bounds__(256) void finalize_kernel(
    const float* __restrict__ partials, int nblocks,
    const float* __restrict__ g, const float* __restrict__ beta,
    float* __restrict__ scsh)
{
    __shared__ float ss[256], sq[256];
    const int c = blockIdx.x;      // channel
    const int tid = threadIdx.x;
    float s = 0.f, q = 0.f;
    for (int b = tid; b < nblocks; b += 256) {
        s += partials[(size_t)b*64 + c];
        q += partials[(size_t)b*64 + CH + c];
    }
    ss[tid] = s; sq[tid] = q;
    __syncthreads();
    for (int st = 128; st > 0; st >>= 1) {
        if (tid < st) { ss[tid] += ss[tid+st]; sq[tid] += sq[tid+st]; }
        __syncthreads();
    }
    if (tid == 0) {
        const float NS = (float)NLOC;
        float mean = ss[0] / NS;
        float var = fmaxf(sq[0] / NS - mean*mean, 0.0f);
        float sc = g[c] / sqrtf(var + BN_EPS);
        scsh[c] = sc;
        scsh[CH + c] = beta[c] - mean*sc;
    }
}

// in-place: bn2 + clampnorm + relu + expmap0 + project on d_out (holding t4)
__global__ __launch_bounds__(256) void out_kernel(
    float* __restrict__ out, const float* __restrict__ scsh)
{
    size_t loc = (size_t)blockIdx.x * 256 + threadIdx.x;   // over N*H*W
    int n = (int)(loc >> 16);
    int hw = (int)(loc & 65535);
    float* p = out + ((size_t)n*CH << 16) + hw;
    float u[CH]; float n2 = 0.f;
    #pragma unroll
    for (int c = 0; c < CH; c++) {
        float t = p[(size_t)c << 16] * scsh[c] + scsh[CH+c];
        u[c] = t; n2 += t*t;
    }
    float nn = sqrtf(n2);
    float f = (nn > R_CLAMP) ? (R_CLAMP/nn) : 1.0f;
    float r2 = 0.f;
    #pragma unroll
    for (int c = 0; c < CH; c++) { float r = fmaxf(u[c]*f, 0.0f); u[c] = r; r2 += r*r; }
    float rn = fmaxf(sqrtf(r2), EPSF);
    float s = fminf(tanhf(rn), MAXN) / rn;   // expmap0 + project combined
    #pragma unroll
    for (int c = 0; c < CH; c++) p[(size_t)c << 16] = u[c]*s;
}

extern "C" void kernel_launch(void* const* d_in, const int* in_sizes, int n_in,
                              void* d_out, int out_size, void* d_ws, size_t ws_size,
                              hipStream_t stream)
{
    const float* x   = (const float*)d_in[0];
    const float* w1  = (const float*)d_in[1];
    const float* b1  = (const float*)d_in[2];
    const float* g1  = (const float*)d_in[3];
    const float* be1 = (const float*)d_in[4];
    const float* w2  = (const float*)d_in[5];
    const float* b2  = (const float*)d_in[6];
    const float* g2  = (const float*)d_in[7];
    const float* be2 = (const float*)d_in[8];
    float* outf = (float*)d_out;

    float* t1 = (float*)d_ws;                        // 16777216 floats (64 MB)
    float* partials = t1 + (size_t)16777216;         // 2048*64 floats
    float* scsh1 = partials + 131072;                // 64 floats
    float* scsh2 = scsh1 + 64;                       // 64 floats

    dim3 grid(HWDIM/TILE, HWDIM/TILE, NB);           // 16 x 16 x 8 = 2048 blocks

    conv_kernel<1><<<grid, 256, 0, stream>>>(x, w1, b1, scsh1 /*unused*/, t1, partials);
    finalize_kernel<<<32, 256, 0, stream>>>(partials, 2048, g1, be1, scsh1);
    conv_kernel<2><<<grid, 256, 0, stream>>>(t1, w2, b2, scsh1, outf /*t4 scratch*/, partials);
    finalize_kernel<<<32, 256, 0, stream>>>(partials, 2048, g2, be2, scsh2);
    out_kernel<<<2048, 256, 0, stream>>>(outf, scsh2);
}

// Round 2
// 907.911 us; speedup vs baseline: 1.0560x; 1.0560x over previous
//
#include <hip/hip_runtime.h>
#include <math.h>

#define HWDIM 256
#define CH 32
#define NB 8
#define TILE 16
#define NLOC (NB*HWDIM*HWDIM)   /* 524288 locations */
#define R_CLAMP 4.9517189f      /* artanh(0.9999) */
#define MAXN 0.9999f            /* (1-1e-4)/sqrt(c) */
#define BN_EPS 1e-5f
#define EPSF 1e-5f

__device__ __forceinline__ float artanh_c(float n) {
    float t = fminf(n, 1.0f - 1e-5f);
    return 0.5f * (log1pf(t) - log1pf(-t));
}

// transpose w[co][ci][3][3] -> wt[ci][co][3][3] so that for fixed ci the
// 288 weights are contiguous => wave-uniform s_load_dwordx16 batches
__global__ __launch_bounds__(256) void wtrans_kernel(
    const float* __restrict__ w, float* __restrict__ wt)
{
    int idx = blockIdx.x * 256 + threadIdx.x;      // linear over src
    if (idx >= CH*CH*9) return;
    int k  = idx % 9;
    int t  = idx / 9;
    int ci = t % CH;
    int co = t / CH;
    wt[(ci*CH + co)*9 + k] = w[idx];
}

// STAGE 1: staging transform = logmap0 (x is in the ball)
// STAGE 2: staging transform = bn1 (scale/shift) + clampnorm + relu
template<int STAGE>
__global__ __launch_bounds__(256) void conv_kernel(
    const float* __restrict__ src,
    const float* __restrict__ wtt,     // [ci][co][3][3]  (transposed)
    const float* __restrict__ bias,    // [CH]
    const float* __restrict__ scsh,    // [2*CH] scale,shift (STAGE 2 only)
    float* __restrict__ dst,
    float* __restrict__ partials)      // [nblocks][64] sums+sumsqs
{
    __shared__ float tile[CH][18][18];
    __shared__ float red[4][64];
    const int tid = threadIdx.x;
    const int bx = blockIdx.x, by = blockIdx.y, bz = blockIdx.z;
    const int h0 = by*TILE - 1, w0 = bx*TILE - 1;
    const float* srcn = src + (size_t)bz*CH*HWDIM*HWDIM;

    // ---- stage global -> LDS (zero halo outside image) ----
    for (int idx = tid; idx < CH*324; idx += 256) {
        int c = idx / 324;
        int r = idx - c*324;
        int y = r / 18, x = r - y*18;
        int gh = h0 + y, gw = w0 + x;
        float v = 0.0f;
        if (gh >= 0 && gh < HWDIM && gw >= 0 && gw < HWDIM)
            v = srcn[((size_t)c*HWDIM + gh)*HWDIM + gw];
        tile[c][y][x] = v;
    }
    __syncthreads();

    // ---- per-location channel transform in LDS ----
    for (int loc = tid; loc < 324; loc += 256) {
        int y = loc / 18, x = loc - y*18;
        int gh = h0 + y, gw = w0 + x;
        if (gh < 0 || gh >= HWDIM || gw < 0 || gw >= HWDIM) continue; // stays zero (padding)
        float v[CH];
        float n2 = 0.0f;
        if (STAGE == 1) {
            #pragma unroll
            for (int c = 0; c < CH; c++) { float t = tile[c][y][x]; v[c] = t; n2 += t*t; }
            float n = fmaxf(sqrtf(n2), EPSF);
            float f = artanh_c(n) / n;
            #pragma unroll
            for (int c = 0; c < CH; c++) tile[c][y][x] = v[c]*f;
        } else {
            #pragma unroll
            for (int c = 0; c < CH; c++) {
                float t = tile[c][y][x] * scsh[c] + scsh[CH + c];
                v[c] = t; n2 += t*t;
            }
            float n = sqrtf(n2);
            float f = (n > R_CLAMP) ? (R_CLAMP / n) : 1.0f;
            #pragma unroll
            for (int c = 0; c < CH; c++) tile[c][y][x] = fmaxf(v[c]*f, 0.0f);
        }
    }
    __syncthreads();

    // ---- direct 3x3 conv: each thread -> one (h,w), all 32 cout ----
    const int tx = tid & 15, ty = tid >> 4;
    float acc[CH];
    #pragma unroll
    for (int co = 0; co < CH; co++) acc[co] = bias[co];

    for (int ci = 0; ci < CH; ci++) {
        float win[9];
        #pragma unroll
        for (int k = 0; k < 9; k++) win[k] = tile[ci][ty + k/3][tx + (k - (k/3)*3)];
        const float* wci = wtt + ci*(CH*9);    // contiguous 288 floats, wave-uniform
        #pragma unroll
        for (int co = 0; co < CH; co++) {
            #pragma unroll
            for (int k = 0; k < 9; k++)
                acc[co] = fmaf(win[k], wci[co*9 + k], acc[co]);
        }
    }

    // ---- clampnorm epilogue + write + BN partial stats ----
    float n2 = 0.0f;
    #pragma unroll
    for (int co = 0; co < CH; co++) n2 += acc[co]*acc[co];
    float nn = sqrtf(n2);
    float f = (nn > R_CLAMP) ? (R_CLAMP / nn) : 1.0f;

    const int h = by*TILE + ty, w = bx*TILE + tx;
    float* dstn = dst + ((size_t)bz*CH*HWDIM + h)*HWDIM + w;
    const int wave = tid >> 6, lane = tid & 63;
    #pragma unroll
    for (int co = 0; co < CH; co++) {
        float val = acc[co] * f;
        dstn[(size_t)co*HWDIM*HWDIM] = val;
        float s = val, q = val*val;
        #pragma unroll
        for (int m = 1; m < 64; m <<= 1) {
            s += __shfl_xor(s, m, 64);
            q += __shfl_xor(q, m, 64);
        }
        if (lane == 0) { red[wave][co] = s; red[wave][CH + co] = q; }
    }
    __syncthreads();
    if (tid < 64) {
        float s = red[0][tid] + red[1][tid] + red[2][tid] + red[3][tid];
        int bid = (bz*gridDim.y + by)*gridDim.x + bx;
        partials[(size_t)bid*64 + tid] = s;
    }
}

__global__ __launch_bounds__(256) void finalize_kernel(
    const float* __restrict__ partials, int nblocks,
    const float* __restrict__ g, const float* __restrict__ beta,
    float* __restrict__ scsh)
{
    __shared__ float ss[256], sq[256];
    const int c = blockIdx.x;      // channel
    const int tid = threadIdx.x;
    float s = 0.f, q = 0.f;
    for (int b = tid; b < nblocks; b += 256) {
        s += partials[(size_t)b*64 + c];
        q += partials[(size_t)b*64 + CH + c];
    }
    ss[tid] = s; sq[tid] = q;
    __syncthreads();
    for (int st = 128; st > 0; st >>= 1) {
        if (tid < st) { ss[tid] += ss[tid+st]; sq[tid] += sq[tid+st]; }
        __syncthreads();
    }
    if (tid == 0) {
        const float NS = (float)NLOC;
        float mean = ss[0] / NS;
        float var = fmaxf(sq[0] / NS - mean*mean, 0.0f);
        float sc = g[c] / sqrtf(var + BN_EPS);
        scsh[c] = sc;
        scsh[CH + c] = beta[c] - mean*sc;
    }
}

// in-place: bn2 + clampnorm + relu + expmap0 + project on d_out (holding t4)
__global__ __launch_bounds__(256) void out_kernel(
    float* __restrict__ out, const float* __restrict__ scsh)
{
    size_t loc = (size_t)blockIdx.x * 256 + threadIdx.x;   // over N*H*W
    int n = (int)(loc >> 16);
    int hw = (int)(loc & 65535);
    float* p = out + ((size_t)n*CH << 16) + hw;
    float u[CH]; float n2 = 0.f;
    #pragma unroll
    for (int c = 0; c < CH; c++) {
        float t = p[(size_t)c << 16] * scsh[c] + scsh[CH+c];
        u[c] = t; n2 += t*t;
    }
    float nn = sqrtf(n2);
    float f = (nn > R_CLAMP) ? (R_CLAMP/nn) : 1.0f;
    float r2 = 0.f;
    #pragma unroll
    for (int c = 0; c < CH; c++) { float r = fmaxf(u[c]*f, 0.0f); u[c] = r; r2 += r*r; }
    float rn = fmaxf(sqrtf(r2), EPSF);
    float s = fminf(tanhf(rn), MAXN) / rn;   // expmap0 + project combined
    #pragma unroll
    for (int c = 0; c < CH; c++) p[(size_t)c << 16] = u[c]*s;
}

extern "C" void kernel_launch(void* const* d_in, const int* in_sizes, int n_in,
                              void* d_out, int out_size, void* d_ws, size_t ws_size,
                              hipStream_t stream)
{
    const float* x   = (const float*)d_in[0];
    const float* w1  = (const float*)d_in[1];
    const float* b1  = (const float*)d_in[2];
    const float* g1  = (const float*)d_in[3];
    const float* be1 = (const float*)d_in[4];
    const float* w2  = (const float*)d_in[5];
    const float* b2  = (const float*)d_in[6];
    const float* g2  = (const float*)d_in[7];
    const float* be2 = (const float*)d_in[8];
    float* outf = (float*)d_out;

    // ws layout: small arrays first, then the big t1 buffer
    float* wtt1     = (float*)d_ws;                  // 9216
    float* wtt2     = wtt1 + 9216;                   // 9216
    float* partials = wtt2 + 9216;                   // 2048*64 = 131072
    float* scsh1    = partials + 131072;             // 64
    float* scsh2    = scsh1 + 64;                    // 64
    float* t1       = scsh2 + 64;                    // 16777216 floats (64 MB)

    wtrans_kernel<<<36, 256, 0, stream>>>(w1, wtt1);
    wtrans_kernel<<<36, 256, 0, stream>>>(w2, wtt2);

    dim3 grid(HWDIM/TILE, HWDIM/TILE, NB);           // 16 x 16 x 8 = 2048 blocks

    conv_kernel<1><<<grid, 256, 0, stream>>>(x, wtt1, b1, scsh1 /*unused*/, t1, partials);
    finalize_kernel<<<32, 256, 0, stream>>>(partials, 2048, g1, be1, scsh1);
    conv_kernel<2><<<grid, 256, 0, stream>>>(t1, wtt2, b2, scsh1, outf /*t4 scratch*/, partials);
    finalize_kernel<<<32, 256, 0, stream>>>(partials, 2048, g2, be2, scsh2);
    out_kernel<<<2048, 256, 0, stream>>>(outf, scsh2);
}

// Round 3
// 318.802 us; speedup vs baseline: 3.0074x; 2.8479x over previous
//
#include <hip/hip_runtime.h>
#include <math.h>

#define HWDIM 256
#define CH 32
#define NB 8
#define TILE 16
#define NLOC (NB*HWDIM*HWDIM)   /* 524288 locations */
#define R_CLAMP 4.9517189f      /* artanh(0.9999) */
#define MAXN 0.9999f
#define BN_EPS 1e-5f
#define EPSF 1e-5f

typedef __attribute__((ext_vector_type(8))) short short8;
typedef __attribute__((ext_vector_type(4))) float floatx4;

__device__ __forceinline__ float artanh_c(float n) {
    float t = fminf(n, 1.0f - 1e-5f);
    return 0.5f * (log1pf(t) - log1pf(-t));
}

__device__ __forceinline__ unsigned short bf16_rn(float f) {
    union { float f; unsigned int u; } c; c.f = f;
    unsigned int u = c.u;
    return (unsigned short)((u + 0x7FFFu + ((u >> 16) & 1u)) >> 16);
}
__device__ __forceinline__ float bf16_to_f(unsigned short h) {
    union { unsigned int u; float f; } c; c.u = ((unsigned int)h) << 16;
    return c.f;
}

// pack w[co][ci][3][3] -> wh/wl[((o*4+g)*32 + co)*8 + j], ci = g*8+j (bf16 hi/lo)
__global__ __launch_bounds__(256) void wprep_kernel(
    const float* __restrict__ w, unsigned short* __restrict__ wh,
    unsigned short* __restrict__ wl)
{
    int idx = blockIdx.x * 256 + threadIdx.x;
    if (idx >= CH*CH*9) return;
    int j  = idx & 7;
    int r  = idx >> 3;          // (o*4+g)*32 + co
    int co = r & 31;
    int og = r >> 5;            // o*4+g
    int g  = og & 3;
    int o  = og >> 2;
    int ci = g*8 + j;
    float v = w[(co*CH + ci)*9 + o];
    unsigned short h = bf16_rn(v);
    wh[idx] = h;
    wl[idx] = bf16_rn(v - bf16_to_f(h));
}

// STAGE 1: staging transform = logmap0; STAGE 2: bn1 + clampnorm + relu
template<int STAGE>
__global__ __launch_bounds__(256) void conv_mfma_kernel(
    const float* __restrict__ src,
    const unsigned short* __restrict__ wph,   // [9][4][32co][8ci] bf16-hi
    const unsigned short* __restrict__ wpl,   // same, bf16-lo
    const float* __restrict__ bias,
    const float* __restrict__ scsh,           // [2*CH] (STAGE 2)
    float* __restrict__ dst,
    float* __restrict__ partials)             // [nblocks][64]
{
    // A-tile hi [18y][4g][18x][8ci] (10368 shorts) + lo (10368) = 41472 B.
    // After compute, aliased as outb[256 loc][36] fp32 (36864 B).
    __shared__ unsigned short smA[20736];
    __shared__ float red[4][64];
    unsigned short* ah = smA;
    unsigned short* al = smA + 10368;
    float* outb = (float*)smA;

    const int tid = threadIdx.x;
    const int bx = blockIdx.x, by = blockIdx.y, bz = blockIdx.z;
    const int h0 = by*TILE - 1, w0 = bx*TILE - 1;
    const float* srcn = src + ((size_t)bz*CH << 16);

    // ---- stage + transform + bf16 hi/lo split into LDS ----
    for (int loc = tid; loc < 324; loc += 256) {
        int y = loc / 18, x = loc - y*18;
        int gh = h0 + y, gw = w0 + x;
        if (gh < 0 || gh >= HWDIM || gw < 0 || gw >= HWDIM) {
            short8 z = {0,0,0,0,0,0,0,0};
            #pragma unroll
            for (int g = 0; g < 4; g++) {
                *(short8*)(ah + ((y*4+g)*18 + x)*8) = z;
                *(short8*)(al + ((y*4+g)*18 + x)*8) = z;
            }
            continue;
        }
        const float* p = srcn + gh*HWDIM + gw;
        float v[CH]; float n2 = 0.f;
        if (STAGE == 1) {
            #pragma unroll
            for (int c = 0; c < CH; c++) { float t = p[(size_t)c << 16]; v[c] = t; n2 = fmaf(t, t, n2); }
            float n = fmaxf(sqrtf(n2), EPSF);
            float f = artanh_c(n) / n;
            #pragma unroll
            for (int c = 0; c < CH; c++) v[c] *= f;
        } else {
            #pragma unroll
            for (int c = 0; c < CH; c++) {
                float t = fmaf(p[(size_t)c << 16], scsh[c], scsh[CH + c]);
                v[c] = t; n2 = fmaf(t, t, n2);
            }
            float n = sqrtf(n2);
            float f = (n > R_CLAMP) ? (R_CLAMP / n) : 1.0f;
            #pragma unroll
            for (int c = 0; c < CH; c++) v[c] = fmaxf(v[c]*f, 0.0f);
        }
        #pragma unroll
        for (int g = 0; g < 4; g++) {
            short8 hv, lv;
            #pragma unroll
            for (int j = 0; j < 8; j++) {
                float t = v[g*8 + j];
                unsigned short h = bf16_rn(t);
                hv[j] = (short)h;
                lv[j] = (short)bf16_rn(t - bf16_to_f(h));
            }
            *(short8*)(ah + ((y*4+g)*18 + x)*8) = hv;
            *(short8*)(al + ((y*4+g)*18 + x)*8) = lv;
        }
    }
    __syncthreads();

    const int lane = tid & 63, wave = tid >> 6;
    const int xx = lane & 15, q = lane >> 4;

    floatx4 acc[4][2];
    #pragma unroll
    for (int i = 0; i < 4; i++) {
        acc[i][0] = (floatx4){0.f,0.f,0.f,0.f};
        acc[i][1] = (floatx4){0.f,0.f,0.f,0.f};
    }

    // ---- implicit GEMM: 9 offsets x K=32, split-bf16 (3 MFMA per product) ----
    #pragma unroll
    for (int o = 0; o < 9; o++) {
        const int dy = o / 3, dx = o - (o/3)*3;
        const unsigned short* wb  = wph + ((o*4 + q)*32)*8;
        const unsigned short* wbl = wpl + ((o*4 + q)*32)*8;
        short8 bh0 = *(const short8*)(wb  + xx*8);
        short8 bh1 = *(const short8*)(wb  + (xx+16)*8);
        short8 bl0 = *(const short8*)(wbl + xx*8);
        short8 bl1 = *(const short8*)(wbl + (xx+16)*8);
        #pragma unroll
        for (int i = 0; i < 4; i++) {
            int yy = wave*4 + i + dy;
            const unsigned short* ap = ah + ((yy*4 + q)*18 + xx + dx)*8;
            short8 a_h = *(const short8*)ap;
            short8 a_l = *(const short8*)(ap + 10368);
            acc[i][0] = __builtin_amdgcn_mfma_f32_16x16x32_bf16(a_h, bh0, acc[i][0], 0,0,0);
            acc[i][1] = __builtin_amdgcn_mfma_f32_16x16x32_bf16(a_h, bh1, acc[i][1], 0,0,0);
            acc[i][0] = __builtin_amdgcn_mfma_f32_16x16x32_bf16(a_l, bh0, acc[i][0], 0,0,0);
            acc[i][1] = __builtin_amdgcn_mfma_f32_16x16x32_bf16(a_l, bh1, acc[i][1], 0,0,0);
            acc[i][0] = __builtin_amdgcn_mfma_f32_16x16x32_bf16(a_h, bl0, acc[i][0], 0,0,0);
            acc[i][1] = __builtin_amdgcn_mfma_f32_16x16x32_bf16(a_h, bl1, acc[i][1], 0,0,0);
        }
    }
    __syncthreads();   // all A reads done before aliasing smA as outb

    // ---- C (reg layout: co=lane&15(+16t), x=q*4+reg, y=wave*4+i) -> LDS ----
    float b0 = bias[xx], b1 = bias[xx + 16];
    #pragma unroll
    for (int i = 0; i < 4; i++) {
        int y = wave*4 + i;
        #pragma unroll
        for (int r = 0; r < 4; r++) {
            int x = q*4 + r;
            outb[(y*16 + x)*36 + xx]      = acc[i][0][r] + b0;
            outb[(y*16 + x)*36 + xx + 16] = acc[i][1][r] + b1;
        }
    }
    __syncthreads();

    // ---- clampnorm + coalesced store + BN partials (thread = one location) ----
    {
        int y = tid >> 4, x = tid & 15;
        float v[CH]; float n2 = 0.f;
        #pragma unroll
        for (int c = 0; c < CH; c++) { float t = outb[tid*36 + c]; v[c] = t; n2 = fmaf(t, t, n2); }
        float nn = sqrtf(n2);
        float f = (nn > R_CLAMP) ? (R_CLAMP / nn) : 1.0f;
        int gh = by*TILE + y, gw = bx*TILE + x;
        float* dp = dst + ((size_t)bz*CH << 16) + gh*HWDIM + gw;
        #pragma unroll
        for (int c = 0; c < CH; c++) {
            float val = v[c]*f;
            dp[(size_t)c << 16] = val;
            float s = val, qq = val*val;
            #pragma unroll
            for (int m = 1; m < 64; m <<= 1) {
                s  += __shfl_xor(s,  m, 64);
                qq += __shfl_xor(qq, m, 64);
            }
            if (lane == 0) { red[wave][c] = s; red[wave][CH + c] = qq; }
        }
    }
    __syncthreads();
    if (tid < 64) {
        float s = red[0][tid] + red[1][tid] + red[2][tid] + red[3][tid];
        int bid = (bz*gridDim.y + by)*gridDim.x + bx;
        partials[(size_t)bid*64 + tid] = s;
    }
}

__global__ __launch_bounds__(256) void finalize_kernel(
    const float* __restrict__ partials, int nblocks,
    const float* __restrict__ g, const float* __restrict__ beta,
    float* __restrict__ scsh)
{
    __shared__ float ss[256], sq[256];
    const int c = blockIdx.x;
    const int tid = threadIdx.x;
    float s = 0.f, q = 0.f;
    for (int b = tid; b < nblocks; b += 256) {
        s += partials[(size_t)b*64 + c];
        q += partials[(size_t)b*64 + CH + c];
    }
    ss[tid] = s; sq[tid] = q;
    __syncthreads();
    for (int st = 128; st > 0; st >>= 1) {
        if (tid < st) { ss[tid] += ss[tid+st]; sq[tid] += sq[tid+st]; }
        __syncthreads();
    }
    if (tid == 0) {
        const float NS = (float)NLOC;
        float mean = ss[0] / NS;
        float var = fmaxf(sq[0] / NS - mean*mean, 0.0f);
        float sc = g[c] / sqrtf(var + BN_EPS);
        scsh[c] = sc;
        scsh[CH + c] = beta[c] - mean*sc;
    }
}

// in-place: bn2 + clampnorm + relu + expmap0 + project on d_out (holding t4)
__global__ __launch_bounds__(256) void out_kernel(
    float* __restrict__ out, const float* __restrict__ scsh)
{
    size_t loc = (size_t)blockIdx.x * 256 + threadIdx.x;
    int n = (int)(loc >> 16);
    int hw = (int)(loc & 65535);
    float* p = out + ((size_t)n*CH << 16) + hw;
    float u[CH]; float n2 = 0.f;
    #pragma unroll
    for (int c = 0; c < CH; c++) {
        float t = fmaf(p[(size_t)c << 16], scsh[c], scsh[CH+c]);
        u[c] = t; n2 = fmaf(t, t, n2);
    }
    float nn = sqrtf(n2);
    float f = (nn > R_CLAMP) ? (R_CLAMP/nn) : 1.0f;
    float r2 = 0.f;
    #pragma unroll
    for (int c = 0; c < CH; c++) { float r = fmaxf(u[c]*f, 0.0f); u[c] = r; r2 = fmaf(r, r, r2); }
    float rn = fmaxf(sqrtf(r2), EPSF);
    float s = fminf(tanhf(rn), MAXN) / rn;
    #pragma unroll
    for (int c = 0; c < CH; c++) p[(size_t)c << 16] = u[c]*s;
}

extern "C" void kernel_launch(void* const* d_in, const int* in_sizes, int n_in,
                              void* d_out, int out_size, void* d_ws, size_t ws_size,
                              hipStream_t stream)
{
    const float* x   = (const float*)d_in[0];
    const float* w1  = (const float*)d_in[1];
    const float* b1  = (const float*)d_in[2];
    const float* g1  = (const float*)d_in[3];
    const float* be1 = (const float*)d_in[4];
    const float* w2  = (const float*)d_in[5];
    const float* b2  = (const float*)d_in[6];
    const float* g2  = (const float*)d_in[7];
    const float* be2 = (const float*)d_in[8];
    float* outf = (float*)d_out;

    char* ws = (char*)d_ws;
    unsigned short* wp1h = (unsigned short*)ws;          // 9216 shorts
    unsigned short* wp1l = wp1h + 9216;
    unsigned short* wp2h = wp1l + 9216;
    unsigned short* wp2l = wp2h + 9216;                  // ends at 73728 B
    float* partials = (float*)(ws + 73728);              // 2048*64 floats
    float* scsh1    = (float*)(ws + 73728 + 524288);     // 64
    float* scsh2    = scsh1 + 64;                        // 64
    float* t1       = scsh2 + 64;                        // 16777216 floats (64 MB)

    wprep_kernel<<<36, 256, 0, stream>>>(w1, wp1h, wp1l);
    wprep_kernel<<<36, 256, 0, stream>>>(w2, wp2h, wp2l);

    dim3 grid(HWDIM/TILE, HWDIM/TILE, NB);               // 16 x 16 x 8 = 2048 blocks

    conv_mfma_kernel<1><<<grid, 256, 0, stream>>>(x, wp1h, wp1l, b1, scsh1, t1, partials);
    finalize_kernel<<<32, 256, 0, stream>>>(partials, 2048, g1, be1, scsh1);
    conv_mfma_kernel<2><<<grid, 256, 0, stream>>>(t1, wp2h, wp2l, b2, scsh1, outf, partials);
    finalize_kernel<<<32, 256, 0, stream>>>(partials, 2048, g2, be2, scsh2);
    out_kernel<<<2048, 256, 0, stream>>>(outf, scsh2);
}

// Round 4
// 267.807 us; speedup vs baseline: 3.5801x; 1.1904x over previous
//
#include <hip/hip_runtime.h>
#include <math.h>

#define HWDIM 256
#define CH 32
#define NB 8
#define TILE 16
#define NLOC (NB*HWDIM*HWDIM)   /* 524288 locations */
#define R_CLAMP 4.9517189f      /* artanh(0.9999) */
#define MAXN 0.9999f
#define BN_EPS 1e-5f
#define EPSF 1e-5f
#define NBLK 2048
#define OSTRIDE 264             /* outb row stride (floats): 264%32=8 -> 2-way-free banks */

typedef __attribute__((ext_vector_type(8))) short short8;
typedef __attribute__((ext_vector_type(4))) float floatx4;

__device__ __forceinline__ float artanh_c(float n) {
    float t = fminf(n, 1.0f - 1e-5f);
    return 0.5f * (log1pf(t) - log1pf(-t));
}
__device__ __forceinline__ unsigned short bf16_rn(float f) {
    union { float f; unsigned int u; } c; c.f = f;
    unsigned int u = c.u;
    return (unsigned short)((u + 0x7FFFu + ((u >> 16) & 1u)) >> 16);
}
__device__ __forceinline__ float bf16_to_f(unsigned short h) {
    union { unsigned int u; float f; } c; c.u = ((unsigned int)h) << 16;
    return c.f;
}

// pack both weight tensors: w[co][ci][3][3] -> wh/wl[((o*4+g)*32+co)*8+j], ci=g*8+j
__global__ __launch_bounds__(256) void wprep_kernel(
    const float* __restrict__ w1, const float* __restrict__ w2,
    unsigned short* __restrict__ wh1, unsigned short* __restrict__ wl1,
    unsigned short* __restrict__ wh2, unsigned short* __restrict__ wl2)
{
    int idx = blockIdx.x * 256 + threadIdx.x;
    if (idx >= 2*CH*CH*9) return;
    int s = idx >= CH*CH*9;
    int id = idx - s*(CH*CH*9);
    const float* w = s ? w2 : w1;
    unsigned short* wh = s ? wh2 : wh1;
    unsigned short* wl = s ? wl2 : wl1;
    int j  = id & 7;
    int r  = id >> 3;
    int co = r & 31;
    int og = r >> 5;
    int g  = og & 3;
    int o  = og >> 2;
    int ci = g*8 + j;
    float v = w[(co*CH + ci)*9 + o];
    unsigned short h = bf16_rn(v);
    wh[id] = h;
    wl[id] = bf16_rn(v - bf16_to_f(h));
}

// STAGE 1: src = x NCHW, staging transform = logmap0, dst = t1 channel-minor [N*H*W][32]
// STAGE 2: src = t1 channel-minor, staging transform = bn1+clampnorm+relu, dst = NCHW
template<int STAGE>
__global__ __launch_bounds__(256) void conv_mfma_kernel(
    const float* __restrict__ src,
    const unsigned short* __restrict__ wph,   // [9][4][32co][8ci] bf16-hi
    const unsigned short* __restrict__ wpl,   // bf16-lo
    const float* __restrict__ bias,
    const float* __restrict__ scsh,           // [2*CH] (STAGE 2)
    float* __restrict__ dst,
    float* __restrict__ partials)             // [64][NBLK] transposed
{
    // A-tile hi [18y][4g][18x][8ci] (10368 sh) + lo (10368) = 41472 B
    // STAGE2: aliased after compute as outb[32co][OSTRIDE] fp32 (33792 B)
    __shared__ unsigned short smA[20736];
    __shared__ float red[4][64];
    unsigned short* ah = smA;
    unsigned short* al = smA + 10368;

    const int tid = threadIdx.x;
    const int bx = blockIdx.x, by = blockIdx.y, bz = blockIdx.z;
    const int h0 = by*TILE - 1, w0 = bx*TILE - 1;

    // ---- stage + transform + bf16 hi/lo split into LDS ----
    for (int loc = tid; loc < 324; loc += 256) {
        int y = loc / 18, x = loc - y*18;
        int gh = h0 + y, gw = w0 + x;
        if (gh < 0 || gh >= HWDIM || gw < 0 || gw >= HWDIM) {
            short8 z = {0,0,0,0,0,0,0,0};
            #pragma unroll
            for (int g = 0; g < 4; g++) {
                *(short8*)(ah + ((y*4+g)*18 + x)*8) = z;
                *(short8*)(al + ((y*4+g)*18 + x)*8) = z;
            }
            continue;
        }
        float v[CH]; float n2 = 0.f;
        if (STAGE == 1) {
            const float* p = src + ((size_t)bz*CH << 16) + gh*HWDIM + gw;
            #pragma unroll
            for (int c = 0; c < CH; c++) { float t = p[(size_t)c << 16]; v[c] = t; n2 = fmaf(t, t, n2); }
            float n = fmaxf(sqrtf(n2), EPSF);
            float f = artanh_c(n) / n;
            #pragma unroll
            for (int c = 0; c < CH; c++) v[c] *= f;
        } else {
            const float* p = src + (((size_t)bz << 16) + gh*HWDIM + gw)*CH;
            floatx4 raw[8];
            #pragma unroll
            for (int k = 0; k < 8; k++) raw[k] = *(const floatx4*)(p + 4*k);
            #pragma unroll
            for (int c = 0; c < CH; c++) {
                float t = fmaf(raw[c>>2][c&3], scsh[c], scsh[CH + c]);
                v[c] = t; n2 = fmaf(t, t, n2);
            }
            float n = sqrtf(n2);
            float f = (n > R_CLAMP) ? (R_CLAMP / n) : 1.0f;
            #pragma unroll
            for (int c = 0; c < CH; c++) v[c] = fmaxf(v[c]*f, 0.0f);
        }
        #pragma unroll
        for (int g = 0; g < 4; g++) {
            short8 hv, lv;
            #pragma unroll
            for (int j = 0; j < 8; j++) {
                float t = v[g*8 + j];
                unsigned short h = bf16_rn(t);
                hv[j] = (short)h;
                lv[j] = (short)bf16_rn(t - bf16_to_f(h));
            }
            *(short8*)(ah + ((y*4+g)*18 + x)*8) = hv;
            *(short8*)(al + ((y*4+g)*18 + x)*8) = lv;
        }
    }
    __syncthreads();

    const int lane = tid & 63, wave = tid >> 6;
    const int xx = lane & 15, q = lane >> 4;

    floatx4 acc[4][2];
    #pragma unroll
    for (int i = 0; i < 4; i++) {
        acc[i][0] = (floatx4){0.f,0.f,0.f,0.f};
        acc[i][1] = (floatx4){0.f,0.f,0.f,0.f};
    }

    // ---- implicit GEMM: dx-outer, A-fragments loaded once (36 distinct) ----
    #pragma unroll
    for (int dx = 0; dx < 3; dx++) {
        short8 afh[6], afl[6];
        #pragma unroll
        for (int yy = 0; yy < 6; yy++) {
            const unsigned short* ap = ah + (((wave*4+yy)*4 + q)*18 + xx + dx)*8;
            afh[yy] = *(const short8*)ap;
            afl[yy] = *(const short8*)(ap + 10368);
        }
        #pragma unroll
        for (int dy = 0; dy < 3; dy++) {
            const int o = dy*3 + dx;
            const unsigned short* wb  = wph + ((o*4 + q)*32)*8;
            const unsigned short* wbl = wpl + ((o*4 + q)*32)*8;
            short8 bh0 = *(const short8*)(wb  + xx*8);
            short8 bh1 = *(const short8*)(wb  + (xx+16)*8);
            short8 bl0 = *(const short8*)(wbl + xx*8);
            short8 bl1 = *(const short8*)(wbl + (xx+16)*8);
            #pragma unroll
            for (int i = 0; i < 4; i++) {
                acc[i][0] = __builtin_amdgcn_mfma_f32_16x16x32_bf16(afh[i+dy], bh0, acc[i][0], 0,0,0);
                acc[i][1] = __builtin_amdgcn_mfma_f32_16x16x32_bf16(afh[i+dy], bh1, acc[i][1], 0,0,0);
                acc[i][0] = __builtin_amdgcn_mfma_f32_16x16x32_bf16(afl[i+dy], bh0, acc[i][0], 0,0,0);
                acc[i][1] = __builtin_amdgcn_mfma_f32_16x16x32_bf16(afl[i+dy], bh1, acc[i][1], 0,0,0);
                acc[i][0] = __builtin_amdgcn_mfma_f32_16x16x32_bf16(afh[i+dy], bl0, acc[i][0], 0,0,0);
                acc[i][1] = __builtin_amdgcn_mfma_f32_16x16x32_bf16(afh[i+dy], bl1, acc[i][1], 0,0,0);
            }
        }
    }

    // ---- register epilogue: bias, per-location clampnorm (quad shuffles), BN partials ----
    {
        float b0 = bias[xx], b1 = bias[xx + 16];
        #pragma unroll
        for (int i = 0; i < 4; i++)
            #pragma unroll
            for (int r = 0; r < 4; r++) { acc[i][0][r] += b0; acc[i][1][r] += b1; }

        #pragma unroll
        for (int i = 0; i < 4; i++) {
            #pragma unroll
            for (int r = 0; r < 4; r++) {
                float n2 = acc[i][0][r]*acc[i][0][r] + acc[i][1][r]*acc[i][1][r];
                n2 += __shfl_xor(n2, 1, 64);
                n2 += __shfl_xor(n2, 2, 64);
                n2 += __shfl_xor(n2, 4, 64);
                n2 += __shfl_xor(n2, 8, 64);
                float nn = sqrtf(n2);
                float f = (nn > R_CLAMP) ? (R_CLAMP/nn) : 1.0f;
                acc[i][0][r] *= f; acc[i][1][r] *= f;
            }
        }
        float s0=0.f, q0=0.f, s1=0.f, q1=0.f;
        #pragma unroll
        for (int i = 0; i < 4; i++)
            #pragma unroll
            for (int r = 0; r < 4; r++) {
                float a0 = acc[i][0][r], a1 = acc[i][1][r];
                s0 += a0; q0 = fmaf(a0, a0, q0);
                s1 += a1; q1 = fmaf(a1, a1, q1);
            }
        s0 += __shfl_xor(s0, 16, 64); s0 += __shfl_xor(s0, 32, 64);
        q0 += __shfl_xor(q0, 16, 64); q0 += __shfl_xor(q0, 32, 64);
        s1 += __shfl_xor(s1, 16, 64); s1 += __shfl_xor(s1, 32, 64);
        q1 += __shfl_xor(q1, 16, 64); q1 += __shfl_xor(q1, 32, 64);
        if (q == 0) {
            red[wave][xx]      = s0;
            red[wave][16 + xx] = s1;
            red[wave][32 + xx] = q0;
            red[wave][48 + xx] = q1;
        }
    }

    const int bid = (bz*gridDim.y + by)*gridDim.x + bx;

    if (STAGE == 1) {
        // direct channel-minor store: t1[(n*65536 + gh*256 + gw)*32 + co]
        float* dp = dst + (((size_t)bz << 16) + (size_t)(by*TILE)*HWDIM + bx*TILE)*CH;
        #pragma unroll
        for (int i = 0; i < 4; i++) {
            int yl = wave*4 + i;
            #pragma unroll
            for (int r = 0; r < 4; r++) {
                int xl = q*4 + r;
                float* a = dp + ((size_t)yl*HWDIM + xl)*CH;
                a[xx]      = acc[i][0][r];
                a[xx + 16] = acc[i][1][r];
            }
        }
        __syncthreads();
        if (tid < 64) {
            float s = red[0][tid] + red[1][tid] + red[2][tid] + red[3][tid];
            partials[(size_t)tid*NBLK + bid] = s;
        }
    } else {
        __syncthreads();   // all smA reads done; red written
        if (tid < 64) {
            float s = red[0][tid] + red[1][tid] + red[2][tid] + red[3][tid];
            partials[(size_t)tid*NBLK + bid] = s;
        }
        float* outb = (float*)smA;   // [32][OSTRIDE]
        #pragma unroll
        for (int i = 0; i < 4; i++) {
            int loc = (wave*4 + i)*16 + q*4;
            *(floatx4*)(outb + (size_t)xx*OSTRIDE + loc)        = acc[i][0];
            *(floatx4*)(outb + (size_t)(xx+16)*OSTRIDE + loc)   = acc[i][1];
        }
        __syncthreads();
        // coalesced NCHW store: thread -> (co = tid>>3, 32 locs)
        const int co = tid >> 3, seg = tid & 7;
        const float* row = outb + (size_t)co*OSTRIDE + seg*32;
        float* gp = dst + ((size_t)(bz*CH + co) << 16) + (size_t)(by*TILE)*HWDIM + bx*TILE;
        #pragma unroll
        for (int k = 0; k < 8; k++) {
            floatx4 vv = *(const floatx4*)(row + 4*k);
            int loc = seg*32 + 4*k;
            int yl = loc >> 4, xl = loc & 15;
            *(floatx4*)(gp + (size_t)yl*HWDIM + xl) = vv;
        }
    }
}

__global__ __launch_bounds__(256) void finalize_kernel(
    const float* __restrict__ partials,
    const float* __restrict__ g, const float* __restrict__ beta,
    float* __restrict__ scsh)
{
    __shared__ float ss[256], sq[256];
    const int c = blockIdx.x;
    const int tid = threadIdx.x;
    float s = 0.f, q = 0.f;
    for (int b = tid; b < NBLK; b += 256) {
        s += partials[(size_t)c*NBLK + b];
        q += partials[(size_t)(CH + c)*NBLK + b];
    }
    ss[tid] = s; sq[tid] = q;
    __syncthreads();
    for (int st = 128; st > 0; st >>= 1) {
        if (tid < st) { ss[tid] += ss[tid+st]; sq[tid] += sq[tid+st]; }
        __syncthreads();
    }
    if (tid == 0) {
        const float NS = (float)NLOC;
        float mean = ss[0] / NS;
        float var = fmaxf(sq[0] / NS - mean*mean, 0.0f);
        float sc = g[c] / sqrtf(var + BN_EPS);
        scsh[c] = sc;
        scsh[CH + c] = beta[c] - mean*sc;
    }
}

// in-place on d_out (NCHW): bn2 + clampnorm + relu + expmap0 + project
__global__ __launch_bounds__(256) void out_kernel(
    float* __restrict__ out, const float* __restrict__ scsh)
{
    size_t loc = (size_t)blockIdx.x * 256 + threadIdx.x;
    int n = (int)(loc >> 16);
    int hw = (int)(loc & 65535);
    float* p = out + ((size_t)n*CH << 16) + hw;
    float u[CH]; float n2 = 0.f;
    #pragma unroll
    for (int c = 0; c < CH; c++) {
        float t = fmaf(p[(size_t)c << 16], scsh[c], scsh[CH+c]);
        u[c] = t; n2 = fmaf(t, t, n2);
    }
    float nn = sqrtf(n2);
    float f = (nn > R_CLAMP) ? (R_CLAMP/nn) : 1.0f;
    float r2 = 0.f;
    #pragma unroll
    for (int c = 0; c < CH; c++) { float r = fmaxf(u[c]*f, 0.0f); u[c] = r; r2 = fmaf(r, r, r2); }
    float rn = fmaxf(sqrtf(r2), EPSF);
    float s = fminf(tanhf(rn), MAXN) / rn;
    #pragma unroll
    for (int c = 0; c < CH; c++) p[(size_t)c << 16] = u[c]*s;
}

extern "C" void kernel_launch(void* const* d_in, const int* in_sizes, int n_in,
                              void* d_out, int out_size, void* d_ws, size_t ws_size,
                              hipStream_t stream)
{
    const float* x   = (const float*)d_in[0];
    const float* w1  = (const float*)d_in[1];
    const float* b1  = (const float*)d_in[2];
    const float* g1  = (const float*)d_in[3];
    const float* be1 = (const float*)d_in[4];
    const float* w2  = (const float*)d_in[5];
    const float* b2  = (const float*)d_in[6];
    const float* g2  = (const float*)d_in[7];
    const float* be2 = (const float*)d_in[8];
    float* outf = (float*)d_out;

    char* ws = (char*)d_ws;
    unsigned short* wp1h = (unsigned short*)ws;          // 9216 shorts
    unsigned short* wp1l = wp1h + 9216;
    unsigned short* wp2h = wp1l + 9216;
    unsigned short* wp2l = wp2h + 9216;                  // 73728 B
    float* partials = (float*)(ws + 73728);              // [64][2048] floats
    float* scsh1    = (float*)(ws + 73728 + 524288);     // 64
    float* scsh2    = scsh1 + 64;                        // 64
    float* t1c      = scsh2 + 64;                        // 16777216 floats, channel-minor

    wprep_kernel<<<72, 256, 0, stream>>>(w1, w2, wp1h, wp1l, wp2h, wp2l);

    dim3 grid(HWDIM/TILE, HWDIM/TILE, NB);               // 2048 blocks

    conv_mfma_kernel<1><<<grid, 256, 0, stream>>>(x, wp1h, wp1l, b1, scsh1, t1c, partials);
    finalize_kernel<<<32, 256, 0, stream>>>(partials, g1, be1, scsh1);
    conv_mfma_kernel<2><<<grid, 256, 0, stream>>>(t1c, wp2h, wp2l, b2, scsh1, outf, partials);
    finalize_kernel<<<32, 256, 0, stream>>>(partials, g2, be2, scsh2);
    out_kernel<<<2048, 256, 0, stream>>>(outf, scsh2);
}

// Round 5
// 226.821 us; speedup vs baseline: 4.2270x; 1.1807x over previous
//
#include <hip/hip_runtime.h>
#include <math.h>

#define HWDIM 256
#define CH 32
#define NB 8
#define TILE 16
#define NLOC (NB*HWDIM*HWDIM)   /* 524288 locations */
#define R_CLAMP 4.9517189f      /* artanh(0.9999) */
#define MAXN 0.9999f
#define BN_EPS 1e-5f
#define EPSF 1e-5f
#define NBLK 2048
#define OST 264                 /* out_kernel LDS row stride (floats) */

typedef __attribute__((ext_vector_type(8))) _Float16 half8;
typedef __attribute__((ext_vector_type(4))) float floatx4;

__device__ __forceinline__ float artanh_c(float n) {
    float t = fminf(n, 1.0f - 1e-5f);
    return 0.5f * (log1pf(t) - log1pf(-t));
}

// pack both weight tensors to fp16: w[co][ci][3][3] -> wp[((o*4+g)*32+co)*8+j], ci=g*8+j
__global__ __launch_bounds__(256) void wprep_kernel(
    const float* __restrict__ w1, const float* __restrict__ w2,
    _Float16* __restrict__ wp1, _Float16* __restrict__ wp2)
{
    int idx = blockIdx.x * 256 + threadIdx.x;
    if (idx >= 2*CH*CH*9) return;
    int s = idx >= CH*CH*9;
    int id = idx - s*(CH*CH*9);
    const float* w = s ? w2 : w1;
    _Float16* wp = s ? wp2 : wp1;
    int j  = id & 7;
    int r  = id >> 3;
    int co = r & 31;
    int og = r >> 5;
    int g  = og & 3;
    int o  = og >> 2;
    int ci = g*8 + j;
    wp[id] = (_Float16)w[(co*CH + ci)*9 + o];
}

// STAGE 1: src = x fp32 NCHW, staging transform = logmap0
// STAGE 2: src = t1 fp16 channel-minor [N*H*W][32], transform = bn1+clampnorm+relu
// dst (both stages): fp16 channel-minor [N*H*W][32]
template<int STAGE>
__global__ __launch_bounds__(256) void conv_mfma_kernel(
    const void* __restrict__ srcv,
    const _Float16* __restrict__ wp,      // [9][4][32co][8ci] fp16
    const float* __restrict__ bias,
    const float* __restrict__ scsh,       // [2*CH] (STAGE 2)
    _Float16* __restrict__ dst,
    float* __restrict__ partials)         // [64][NBLK] transposed
{
    __shared__ _Float16 ah[10368];        // [18y][4g][18x][8ci] = 20736 B
    __shared__ float red[4][64];

    const int tid = threadIdx.x;
    const int bx = blockIdx.x, by = blockIdx.y, bz = blockIdx.z;
    const int h0 = by*TILE - 1, w0 = bx*TILE - 1;

    // ---- stage + transform -> fp16 A-tile in LDS ----
    for (int loc = tid; loc < 324; loc += 256) {
        int y = loc / 18, x = loc - y*18;
        int gh = h0 + y, gw = w0 + x;
        if (gh < 0 || gh >= HWDIM || gw < 0 || gw >= HWDIM) {
            half8 z = {0,0,0,0,0,0,0,0};
            #pragma unroll
            for (int g = 0; g < 4; g++) *(half8*)(ah + ((y*4+g)*18 + x)*8) = z;
            continue;
        }
        float v[CH]; float n2 = 0.f;
        if (STAGE == 1) {
            const float* p = (const float*)srcv + ((size_t)bz*CH << 16) + gh*HWDIM + gw;
            #pragma unroll
            for (int c = 0; c < CH; c++) { float t = p[(size_t)c << 16]; v[c] = t; n2 = fmaf(t, t, n2); }
            float n = fmaxf(sqrtf(n2), EPSF);
            float f = artanh_c(n) / n;
            #pragma unroll
            for (int c = 0; c < CH; c++) v[c] *= f;
        } else {
            const _Float16* p = (const _Float16*)srcv + (((size_t)bz << 16) + gh*HWDIM + gw)*CH;
            half8 raw[4];
            #pragma unroll
            for (int k = 0; k < 4; k++) raw[k] = *(const half8*)(p + 8*k);
            #pragma unroll
            for (int c = 0; c < CH; c++) {
                float t = fmaf((float)raw[c>>3][c&7], scsh[c], scsh[CH + c]);
                v[c] = t; n2 = fmaf(t, t, n2);
            }
            float n = sqrtf(n2);
            float f = (n > R_CLAMP) ? (R_CLAMP / n) : 1.0f;
            #pragma unroll
            for (int c = 0; c < CH; c++) v[c] = fmaxf(v[c]*f, 0.0f);
        }
        #pragma unroll
        for (int g = 0; g < 4; g++) {
            half8 hv;
            #pragma unroll
            for (int j = 0; j < 8; j++) hv[j] = (_Float16)v[g*8 + j];
            *(half8*)(ah + ((y*4+g)*18 + x)*8) = hv;
        }
    }
    __syncthreads();

    const int lane = tid & 63, wave = tid >> 6;
    const int xx = lane & 15, q = lane >> 4;

    floatx4 acc[4][2];
    #pragma unroll
    for (int i = 0; i < 4; i++) {
        acc[i][0] = (floatx4){0.f,0.f,0.f,0.f};
        acc[i][1] = (floatx4){0.f,0.f,0.f,0.f};
    }

    // ---- implicit GEMM: 9 offsets x K=32, single fp16 MFMA per product ----
    #pragma unroll
    for (int dx = 0; dx < 3; dx++) {
        half8 af[6];
        #pragma unroll
        for (int yy = 0; yy < 6; yy++)
            af[yy] = *(const half8*)(ah + (((wave*4+yy)*4 + q)*18 + xx + dx)*8);
        #pragma unroll
        for (int dy = 0; dy < 3; dy++) {
            const int o = dy*3 + dx;
            const _Float16* wb = wp + (size_t)((o*4 + q)*32)*8;
            half8 b0 = *(const half8*)(wb + xx*8);
            half8 b1 = *(const half8*)(wb + (xx+16)*8);
            #pragma unroll
            for (int i = 0; i < 4; i++) {
                acc[i][0] = __builtin_amdgcn_mfma_f32_16x16x32_f16(af[i+dy], b0, acc[i][0], 0,0,0);
                acc[i][1] = __builtin_amdgcn_mfma_f32_16x16x32_f16(af[i+dy], b1, acc[i][1], 0,0,0);
            }
        }
    }

    // ---- register epilogue: bias, per-location clampnorm, BN partials ----
    {
        float b0 = bias[xx], b1 = bias[xx + 16];
        #pragma unroll
        for (int i = 0; i < 4; i++)
            #pragma unroll
            for (int r = 0; r < 4; r++) { acc[i][0][r] += b0; acc[i][1][r] += b1; }

        #pragma unroll
        for (int i = 0; i < 4; i++) {
            #pragma unroll
            for (int r = 0; r < 4; r++) {
                float n2 = acc[i][0][r]*acc[i][0][r] + acc[i][1][r]*acc[i][1][r];
                n2 += __shfl_xor(n2, 1, 64);
                n2 += __shfl_xor(n2, 2, 64);
                n2 += __shfl_xor(n2, 4, 64);
                n2 += __shfl_xor(n2, 8, 64);
                float nn = sqrtf(n2);
                float f = (nn > R_CLAMP) ? (R_CLAMP/nn) : 1.0f;
                acc[i][0][r] *= f; acc[i][1][r] *= f;
            }
        }
        float s0=0.f, q0=0.f, s1=0.f, q1=0.f;
        #pragma unroll
        for (int i = 0; i < 4; i++)
            #pragma unroll
            for (int r = 0; r < 4; r++) {
                float a0 = acc[i][0][r], a1 = acc[i][1][r];
                s0 += a0; q0 = fmaf(a0, a0, q0);
                s1 += a1; q1 = fmaf(a1, a1, q1);
            }
        s0 += __shfl_xor(s0, 16, 64); s0 += __shfl_xor(s0, 32, 64);
        q0 += __shfl_xor(q0, 16, 64); q0 += __shfl_xor(q0, 32, 64);
        s1 += __shfl_xor(s1, 16, 64); s1 += __shfl_xor(s1, 32, 64);
        q1 += __shfl_xor(q1, 16, 64); q1 += __shfl_xor(q1, 32, 64);
        if (q == 0) {
            red[wave][xx]      = s0;
            red[wave][16 + xx] = s1;
            red[wave][32 + xx] = q0;
            red[wave][48 + xx] = q1;
        }
    }

    // ---- fp16 channel-minor store: dst[(n*65536 + gh*256 + gw)*32 + co] ----
    {
        _Float16* dp = dst + (((size_t)bz << 16) + (size_t)(by*TILE)*HWDIM + bx*TILE)*CH;
        #pragma unroll
        for (int i = 0; i < 4; i++) {
            int yl = wave*4 + i;
            #pragma unroll
            for (int r = 0; r < 4; r++) {
                int xl = q*4 + r;
                _Float16* a = dp + ((size_t)yl*HWDIM + xl)*CH;
                a[xx]      = (_Float16)acc[i][0][r];
                a[xx + 16] = (_Float16)acc[i][1][r];
            }
        }
    }
    __syncthreads();
    if (tid < 64) {
        float s = red[0][tid] + red[1][tid] + red[2][tid] + red[3][tid];
        int bid = (bz*gridDim.y + by)*gridDim.x + bx;
        partials[(size_t)tid*NBLK + bid] = s;
    }
}

__global__ __launch_bounds__(256) void finalize_kernel(
    const float* __restrict__ partials,
    const float* __restrict__ g, const float* __restrict__ beta,
    float* __restrict__ scsh)
{
    __shared__ float ss[256], sq[256];
    const int c = blockIdx.x;
    const int tid = threadIdx.x;
    float s = 0.f, q = 0.f;
    for (int b = tid; b < NBLK; b += 256) {
        s += partials[(size_t)c*NBLK + b];
        q += partials[(size_t)(CH + c)*NBLK + b];
    }
    ss[tid] = s; sq[tid] = q;
    __syncthreads();
    for (int st = 128; st > 0; st >>= 1) {
        if (tid < st) { ss[tid] += ss[tid+st]; sq[tid] += sq[tid+st]; }
        __syncthreads();
    }
    if (tid == 0) {
        const float NS = (float)NLOC;
        float mean = ss[0] / NS;
        float var = fmaxf(sq[0] / NS - mean*mean, 0.0f);
        float sc = g[c] / sqrtf(var + BN_EPS);
        scsh[c] = sc;
        scsh[CH + c] = beta[c] - mean*sc;
    }
}

// read t4 fp16 channel-minor; bn2+clampnorm+relu+expmap0+project; write fp32 NCHW
__global__ __launch_bounds__(256) void out_kernel(
    const _Float16* __restrict__ t4c, const float* __restrict__ scsh,
    float* __restrict__ out)
{
    __shared__ float outb[16*OST];
    const int w = threadIdx.x;
    const int h = blockIdx.x, n = blockIdx.y;
    const _Float16* p = t4c + (((size_t)n << 16) + (size_t)h*HWDIM + w)*CH;
    half8 raw[4];
    #pragma unroll
    for (int k = 0; k < 4; k++) raw[k] = *(const half8*)(p + 8*k);
    float u[CH]; float n2 = 0.f;
    #pragma unroll
    for (int c = 0; c < CH; c++) {
        float t = fmaf((float)raw[c>>3][c&7], scsh[c], scsh[CH+c]);
        u[c] = t; n2 = fmaf(t, t, n2);
    }
    float nn = sqrtf(n2);
    float f = (nn > R_CLAMP) ? (R_CLAMP/nn) : 1.0f;
    float r2 = 0.f;
    #pragma unroll
    for (int c = 0; c < CH; c++) { float r = fmaxf(u[c]*f, 0.0f); u[c] = r; r2 = fmaf(r, r, r2); }
    float rn = fmaxf(sqrtf(r2), EPSF);
    float s = fminf(tanhf(rn), MAXN) / rn;
    #pragma unroll
    for (int c = 0; c < CH; c++) u[c] *= s;

    #pragma unroll
    for (int hf = 0; hf < 2; hf++) {
        if (hf) __syncthreads();
        #pragma unroll
        for (int c = 0; c < 16; c++) outb[c*OST + w] = u[hf*16 + c];
        __syncthreads();
        int co = threadIdx.x >> 4, seg = threadIdx.x & 15;
        const float* row = outb + co*OST + seg*16;
        float* gp = out + ((size_t)(n*CH + hf*16 + co) << 16) + (size_t)h*HWDIM + seg*16;
        #pragma unroll
        for (int k = 0; k < 4; k++) *(floatx4*)(gp + 4*k) = *(const floatx4*)(row + 4*k);
    }
}

extern "C" void kernel_launch(void* const* d_in, const int* in_sizes, int n_in,
                              void* d_out, int out_size, void* d_ws, size_t ws_size,
                              hipStream_t stream)
{
    const float* x   = (const float*)d_in[0];
    const float* w1  = (const float*)d_in[1];
    const float* b1  = (const float*)d_in[2];
    const float* g1  = (const float*)d_in[3];
    const float* be1 = (const float*)d_in[4];
    const float* w2  = (const float*)d_in[5];
    const float* b2  = (const float*)d_in[6];
    const float* g2  = (const float*)d_in[7];
    const float* be2 = (const float*)d_in[8];
    float* outf = (float*)d_out;

    char* ws = (char*)d_ws;
    _Float16* wp1   = (_Float16*)ws;                     // 9216 halves
    _Float16* wp2   = wp1 + 9216;                        // 9216 halves -> 36864 B
    float* partials = (float*)(ws + 36864);              // [64][2048] floats
    float* scsh1    = (float*)(ws + 36864 + 524288);     // 64
    float* scsh2    = scsh1 + 64;                        // 64
    _Float16* t1c   = (_Float16*)(scsh2 + 64);           // 16.7M halves (32 MB)
    _Float16* t4c   = t1c + (size_t)NLOC*CH;             // 16.7M halves (32 MB)

    wprep_kernel<<<72, 256, 0, stream>>>(w1, w2, wp1, wp2);

    dim3 grid(HWDIM/TILE, HWDIM/TILE, NB);               // 2048 blocks

    conv_mfma_kernel<1><<<grid, 256, 0, stream>>>(x, wp1, b1, scsh1, t1c, partials);
    finalize_kernel<<<32, 256, 0, stream>>>(partials, g1, be1, scsh1);
    conv_mfma_kernel<2><<<grid, 256, 0, stream>>>(t1c, wp2, b2, scsh1, t4c, partials);
    finalize_kernel<<<32, 256, 0, stream>>>(partials, g2, be2, scsh2);
    out_kernel<<<dim3(HWDIM, NB), 256, 0, stream>>>(t4c, scsh2, outf);
}

// Round 6
// 204.482 us; speedup vs baseline: 4.6888x; 1.1092x over previous
//
#include <hip/hip_runtime.h>
#include <math.h>

#define HWDIM 256
#define CH 32
#define NB 8
#define TILE 16
#define NLOC (NB*HWDIM*HWDIM)   /* 524288 locations */
#define R_CLAMP 4.9517189f      /* artanh(0.9999) */
#define MAXN 0.9999f
#define BN_EPS 1e-5f
#define EPSF 1e-5f
#define NBLK 2048
#define OST 264                 /* out_kernel LDS row stride (floats) */

typedef __attribute__((ext_vector_type(8))) _Float16 half8;
typedef __attribute__((ext_vector_type(4))) _Float16 half4;
typedef __attribute__((ext_vector_type(4))) float floatx4;

__device__ __forceinline__ float artanh_c(float n) {
    float t = fminf(n, 1.0f - 1e-5f);
    return 0.5f * (log1pf(t) - log1pf(-t));
}

// pack both weight tensors to fp16: w[co][ci][3][3] -> wp[((o*4+g)*32+co)*8+j], ci=g*8+j
__global__ __launch_bounds__(256) void wprep_kernel(
    const float* __restrict__ w1, const float* __restrict__ w2,
    _Float16* __restrict__ wp1, _Float16* __restrict__ wp2)
{
    int idx = blockIdx.x * 256 + threadIdx.x;
    if (idx >= 2*CH*CH*9) return;
    int s = idx >= CH*CH*9;
    int id = idx - s*(CH*CH*9);
    const float* w = s ? w2 : w1;
    _Float16* wp = s ? wp2 : wp1;
    int j  = id & 7;
    int r  = id >> 3;
    int co = r & 31;
    int og = r >> 5;
    int g  = og & 3;
    int o  = og >> 2;
    int ci = g*8 + j;
    wp[id] = (_Float16)w[(co*CH + ci)*9 + o];
}

// STAGE 1: src = x fp32 NCHW, staging transform = logmap0
// STAGE 2: src = t1 fp16 channel-minor [N*H*W][32], transform = bn1+clampnorm+relu
// dst (both stages): fp16 channel-minor [N*H*W][32]
template<int STAGE>
__global__ __launch_bounds__(256) void conv_mfma_kernel(
    const void* __restrict__ srcv,
    const _Float16* __restrict__ wp,      // [9][4][32co][8ci] fp16
    const float* __restrict__ bias,
    const float* __restrict__ scsh,       // [2*CH] (STAGE 2)
    _Float16* __restrict__ dst,
    float* __restrict__ partials)         // [64][NBLK] transposed
{
    __shared__ _Float16 ah[10368];        // [18y][4g][18x][8ci] = 20736 B
    __shared__ float red[4][64];

    const int tid = threadIdx.x;
    // XCD-aware swizzle: flat&7 -> image index, so each XCD rasters one image
    const int flat = blockIdx.x;
    const int bz = flat & 7;
    const int t  = flat >> 3;
    const int by = t >> 4, bx = t & 15;
    const int h0 = by*TILE - 1, w0 = bx*TILE - 1;

    // ---- stage + transform -> fp16 A-tile in LDS ----
    for (int loc = tid; loc < 324; loc += 256) {
        int y = loc / 18, x = loc - y*18;
        int gh = h0 + y, gw = w0 + x;
        if (gh < 0 || gh >= HWDIM || gw < 0 || gw >= HWDIM) {
            half8 z = {0,0,0,0,0,0,0,0};
            #pragma unroll
            for (int g = 0; g < 4; g++) *(half8*)(ah + ((y*4+g)*18 + x)*8) = z;
            continue;
        }
        float v[CH]; float n2 = 0.f;
        if (STAGE == 1) {
            const float* p = (const float*)srcv + ((size_t)bz*CH << 16) + gh*HWDIM + gw;
            #pragma unroll
            for (int c = 0; c < CH; c++) { float t0 = p[(size_t)c << 16]; v[c] = t0; n2 = fmaf(t0, t0, n2); }
            float n = fmaxf(sqrtf(n2), EPSF);
            float f = artanh_c(n) / n;
            #pragma unroll
            for (int c = 0; c < CH; c++) v[c] *= f;
        } else {
            const _Float16* p = (const _Float16*)srcv + (((size_t)bz << 16) + gh*HWDIM + gw)*CH;
            half8 raw[4];
            #pragma unroll
            for (int k = 0; k < 4; k++) raw[k] = *(const half8*)(p + 8*k);
            #pragma unroll
            for (int c = 0; c < CH; c++) {
                float t0 = fmaf((float)raw[c>>3][c&7], scsh[c], scsh[CH + c]);
                v[c] = t0; n2 = fmaf(t0, t0, n2);
            }
            float n = sqrtf(n2);
            float f = (n > R_CLAMP) ? (R_CLAMP / n) : 1.0f;
            #pragma unroll
            for (int c = 0; c < CH; c++) v[c] = fmaxf(v[c]*f, 0.0f);
        }
        #pragma unroll
        for (int g = 0; g < 4; g++) {
            half8 hv;
            #pragma unroll
            for (int j = 0; j < 8; j++) hv[j] = (_Float16)v[g*8 + j];
            *(half8*)(ah + ((y*4+g)*18 + x)*8) = hv;
        }
    }
    __syncthreads();

    const int lane = tid & 63, wave = tid >> 6;
    const int xx = lane & 15, q = lane >> 4;

    floatx4 acc[4][2];
    #pragma unroll
    for (int i = 0; i < 4; i++) {
        acc[i][0] = (floatx4){0.f,0.f,0.f,0.f};
        acc[i][1] = (floatx4){0.f,0.f,0.f,0.f};
    }

    // ---- implicit GEMM, swapped operands: A = weights (m=co), B = acts (n=loc) ----
    // D[m=co=q*4+r(+16h)][n=loc x=xx] per loc-tile i (y = wave*4+i)
    #pragma unroll
    for (int dx = 0; dx < 3; dx++) {
        half8 af[6];
        #pragma unroll
        for (int yy = 0; yy < 6; yy++)
            af[yy] = *(const half8*)(ah + (((wave*4+yy)*4 + q)*18 + xx + dx)*8);
        #pragma unroll
        for (int dy = 0; dy < 3; dy++) {
            const int o = dy*3 + dx;
            const _Float16* wb = wp + (size_t)((o*4 + q)*32)*8;
            half8 wf0 = *(const half8*)(wb + xx*8);          // A[m=xx][k=q*8+j], co 0..15
            half8 wf1 = *(const half8*)(wb + (xx+16)*8);     // co 16..31
            #pragma unroll
            for (int i = 0; i < 4; i++) {
                acc[i][0] = __builtin_amdgcn_mfma_f32_16x16x32_f16(wf0, af[i+dy], acc[i][0], 0,0,0);
                acc[i][1] = __builtin_amdgcn_mfma_f32_16x16x32_f16(wf1, af[i+dy], acc[i][1], 0,0,0);
            }
        }
    }

    // ---- register epilogue: thread owns ch {q*4+r, q*4+r+16} of loc (y=wave*4+i, x=xx) ----
    float bs[8];
    #pragma unroll
    for (int r = 0; r < 4; r++) { bs[r] = bias[q*4+r]; bs[4+r] = bias[q*4+r+16]; }
    float sv[8], qv[8];
    #pragma unroll
    for (int k = 0; k < 8; k++) { sv[k] = 0.f; qv[k] = 0.f; }

    _Float16* dp = dst + (((size_t)bz << 16) + (size_t)(by*TILE)*HWDIM + bx*TILE + xx)*CH + q*4;

    #pragma unroll
    for (int i = 0; i < 4; i++) {
        float n2 = 0.f;
        #pragma unroll
        for (int r = 0; r < 4; r++) {
            acc[i][0][r] += bs[r];
            acc[i][1][r] += bs[4+r];
            n2 = fmaf(acc[i][0][r], acc[i][0][r], n2);
            n2 = fmaf(acc[i][1][r], acc[i][1][r], n2);
        }
        n2 += __shfl_xor(n2, 16, 64);
        n2 += __shfl_xor(n2, 32, 64);
        float nn = sqrtf(n2);
        float f = (nn > R_CLAMP) ? (R_CLAMP/nn) : 1.0f;
        half4 o0, o1;
        #pragma unroll
        for (int r = 0; r < 4; r++) {
            float a0 = acc[i][0][r] * f;
            float a1 = acc[i][1][r] * f;
            sv[r]   += a0; qv[r]   = fmaf(a0, a0, qv[r]);
            sv[4+r] += a1; qv[4+r] = fmaf(a1, a1, qv[4+r]);
            o0[r] = (_Float16)a0; o1[r] = (_Float16)a1;
        }
        _Float16* a = dp + (size_t)(wave*4 + i)*HWDIM*CH;
        *(half4*)(a)      = o0;
        *(half4*)(a + 16) = o1;
    }

    // quad-reduce BN partials over the 16 xx-lanes
    #pragma unroll
    for (int k = 0; k < 8; k++) {
        #pragma unroll
        for (int m = 1; m < 16; m <<= 1) {
            sv[k] += __shfl_xor(sv[k], m, 64);
            qv[k] += __shfl_xor(qv[k], m, 64);
        }
    }
    if (xx == 0) {
        #pragma unroll
        for (int r = 0; r < 4; r++) {
            red[wave][q*4+r]        = sv[r];
            red[wave][16 + q*4+r]   = sv[4+r];
            red[wave][32 + q*4+r]   = qv[r];
            red[wave][48 + q*4+r]   = qv[4+r];
        }
    }
    __syncthreads();
    if (tid < 64) {
        float s = red[0][tid] + red[1][tid] + red[2][tid] + red[3][tid];
        partials[(size_t)tid*NBLK + flat] = s;
    }
}

__global__ __launch_bounds__(256) void finalize_kernel(
    const float* __restrict__ partials,
    const float* __restrict__ g, const float* __restrict__ beta,
    float* __restrict__ scsh)
{
    __shared__ float ss[256], sq[256];
    const int c = blockIdx.x;
    const int tid = threadIdx.x;
    float s = 0.f, q = 0.f;
    for (int b = tid; b < NBLK; b += 256) {
        s += partials[(size_t)c*NBLK + b];
        q += partials[(size_t)(CH + c)*NBLK + b];
    }
    ss[tid] = s; sq[tid] = q;
    __syncthreads();
    for (int st = 128; st > 0; st >>= 1) {
        if (tid < st) { ss[tid] += ss[tid+st]; sq[tid] += sq[tid+st]; }
        __syncthreads();
    }
    if (tid == 0) {
        const float NS = (float)NLOC;
        float mean = ss[0] / NS;
        float var = fmaxf(sq[0] / NS - mean*mean, 0.0f);
        float sc = g[c] / sqrtf(var + BN_EPS);
        scsh[c] = sc;
        scsh[CH + c] = beta[c] - mean*sc;
    }
}

// read t4 fp16 channel-minor; bn2+clampnorm+relu+expmap0+project; write fp32 NCHW
__global__ __launch_bounds__(256) void out_kernel(
    const _Float16* __restrict__ t4c, const float* __restrict__ scsh,
    float* __restrict__ out)
{
    __shared__ float outb[16*OST];
    const int w = threadIdx.x;
    const int h = blockIdx.x, n = blockIdx.y;
    const _Float16* p = t4c + (((size_t)n << 16) + (size_t)h*HWDIM + w)*CH;
    half8 raw[4];
    #pragma unroll
    for (int k = 0; k < 4; k++) raw[k] = *(const half8*)(p + 8*k);
    float u[CH]; float n2 = 0.f;
    #pragma unroll
    for (int c = 0; c < CH; c++) {
        float t = fmaf((float)raw[c>>3][c&7], scsh[c], scsh[CH+c]);
        u[c] = t; n2 = fmaf(t, t, n2);
    }
    float nn = sqrtf(n2);
    float f = (nn > R_CLAMP) ? (R_CLAMP/nn) : 1.0f;
    float r2 = 0.f;
    #pragma unroll
    for (int c = 0; c < CH; c++) { float r = fmaxf(u[c]*f, 0.0f); u[c] = r; r2 = fmaf(r, r, r2); }
    float rn = fmaxf(sqrtf(r2), EPSF);
    float s = fminf(tanhf(rn), MAXN) / rn;
    #pragma unroll
    for (int c = 0; c < CH; c++) u[c] *= s;

    #pragma unroll
    for (int hf = 0; hf < 2; hf++) {
        if (hf) __syncthreads();
        #pragma unroll
        for (int c = 0; c < 16; c++) outb[c*OST + w] = u[hf*16 + c];
        __syncthreads();
        int co = threadIdx.x >> 4, seg = threadIdx.x & 15;
        const float* row = outb + co*OST + seg*16;
        float* gp = out + ((size_t)(n*CH + hf*16 + co) << 16) + (size_t)h*HWDIM + seg*16;
        #pragma unroll
        for (int k = 0; k < 4; k++) *(floatx4*)(gp + 4*k) = *(const floatx4*)(row + 4*k);
    }
}

extern "C" void kernel_launch(void* const* d_in, const int* in_sizes, int n_in,
                              void* d_out, int out_size, void* d_ws, size_t ws_size,
                              hipStream_t stream)
{
    const float* x   = (const float*)d_in[0];
    const float* w1  = (const float*)d_in[1];
    const float* b1  = (const float*)d_in[2];
    const float* g1  = (const float*)d_in[3];
    const float* be1 = (const float*)d_in[4];
    const float* w2  = (const float*)d_in[5];
    const float* b2  = (const float*)d_in[6];
    const float* g2  = (const float*)d_in[7];
    const float* be2 = (const float*)d_in[8];
    float* outf = (float*)d_out;

    char* ws = (char*)d_ws;
    _Float16* wp1   = (_Float16*)ws;                     // 9216 halves
    _Float16* wp2   = wp1 + 9216;                        // 9216 halves -> 36864 B
    float* partials = (float*)(ws + 36864);              // [64][2048] floats
    float* scsh1    = (float*)(ws + 36864 + 524288);     // 64
    float* scsh2    = scsh1 + 64;                        // 64
    _Float16* t1c   = (_Float16*)(scsh2 + 64);           // 16.7M halves (32 MB)
    _Float16* t4c   = t1c + (size_t)NLOC*CH;             // 16.7M halves (32 MB)

    wprep_kernel<<<72, 256, 0, stream>>>(w1, w2, wp1, wp2);

    conv_mfma_kernel<1><<<NBLK, 256, 0, stream>>>(x, wp1, b1, scsh1, t1c, partials);
    finalize_kernel<<<32, 256, 0, stream>>>(partials, g1, be1, scsh1);
    conv_mfma_kernel<2><<<NBLK, 256, 0, stream>>>(t1c, wp2, b2, scsh1, t4c, partials);
    finalize_kernel<<<32, 256, 0, stream>>>(partials, g2, be2, scsh2);
    out_kernel<<<dim3(HWDIM, NB), 256, 0, stream>>>(t4c, scsh2, outf);
}